// Round 3
// baseline (1077.438 us; speedup 1.0000x reference)
//
#include <hip/hip_runtime.h>
#include <math.h>

#define HID 128
#define NSTEPS 64
#define SLEN 65
#define THREADS 256
#define ROWS 32       // R15: 32 rows/WG -> grid 1024 -> 4 WGs/CU, 4 waves/SIMD
#define ASTRIDE 136   // 128 + 8 f16 pad, 16B aligned rows (R13 layout, swizzle reverted)
#define FSTRIDE 40    // 32 + 8 f16 pad
#define DSTR 68       // 64 + 4 f32 pad, 16B-aligned rows for b128 flush reads

typedef _Float16 half8 __attribute__((ext_vector_type(8)));
typedef __fp16 fp16x2 __attribute__((ext_vector_type(2)));
typedef float floatx4 __attribute__((ext_vector_type(4)));

// R15 = R13 geometry change: ROWS 64->32 (grid 512->1024).
// WHY: occupancy was grid-limited, not reg/LDS-limited. ROWS=64 gives only
// 512 WGs = 2 WGs/CU = 2 waves/SIMD; with 6 barriers/step every phase is a
// dependent ds_read->MFMA->EPI chain and 2 waves/SIMD cannot hide it (wall
// 14.2k cyc/step/CU vs ~5-7k busy on the busiest pipe). ROWS=32 doubles
// co-resident waves (4 WGs/CU, 16 waves/CU) and gives 4 independent barrier
// groups/CU. Per-CU MFMA/VALU/LDS totals unchanged. LDS 36.4KB/WG x4=145.5
// <=160. launch_bounds(256,4).
// R14 CLOSED: XOR swizzle -> SQ_LDS_BANK_CONFLICT bit-identical 3.808e7;
// counter is structural b128 intra-instruction serialization (1024B/wave
// read = 8 LDS cyc minimum; both layouts already at 8 lanes/4-bank slot).
// Swizzle also defeated offset:N addressing -> scratch traffic -> +33us.
// R13 (kept): MFMA Wf-dot w/ broadcast B; zero global ops in k-loop (S in
// LDS, deltas staged, coalesced flush); 16-lane sigmoid.
// CLOSED paths: residual-in-regs spills (R10/R11); 64-col/wave spills (R3);
// 32x32 MFMA; 6 barriers = dependency minimum; LDS-layout conflict fixes.
__global__ __launch_bounds__(THREADS, 4)
void hedger(const float* __restrict__ S,
            const float* __restrict__ W0,  const float* __restrict__ b0,
            const float* __restrict__ rW1, const float* __restrict__ rb1,
            const float* __restrict__ rW2, const float* __restrict__ rb2,
            const float* __restrict__ sW1, const float* __restrict__ sb1,
            const float* __restrict__ sW2, const float* __restrict__ sb2,
            const float* __restrict__ Wf,  const float* __restrict__ bfp,
            float* __restrict__ out)
{
  __shared__ __align__(16) _Float16 bufA[ROWS * ASTRIDE];
  __shared__ __align__(16) _Float16 bufB[ROWS * ASTRIDE];
  __shared__ __align__(16) _Float16 featb[ROWS * FSTRIDE];
  __shared__ __align__(16) _Float16 WfS[HID];
  __shared__ __align__(16) float    Slds[ROWS * SLEN];
  __shared__ __align__(16) float    deltab[ROWS * DSTR];

  const int tid  = threadIdx.x;
  const int wave = tid >> 6;            // 0..3
  const int lane = tid & 63;
  const int l15  = lane & 15;
  const int quad = lane >> 4;
  const int n_base = wave * 32;
  const int r0 = blockIdx.x * ROWS;
  const int col0 = n_base + 2 * l15;    // lane's adjacent column pair

  // ---- persistent B fragments (128 VGPR): n = col0 + nt, k = quad*8 + j.
  half8 wfrag[4][4][2];  // [matrix][kIter][nt]
  {
    const float* Wm[4] = {rW1, rW2, sW1, sW2};
#pragma unroll
    for (int m = 0; m < 4; ++m)
#pragma unroll
      for (int kq = 0; kq < 4; ++kq)
#pragma unroll
        for (int nt = 0; nt < 2; ++nt) {
          const int n  = col0 + nt;
          const int kb = kq * 32 + quad * 8;
          half8 f;
#pragma unroll
          for (int j = 0; j < 8; ++j)
            f[j] = (_Float16)Wm[m][(kb + j) * HID + n];
          wfrag[m][kq][nt] = f;
        }
  }
  // W0 (8x128) zero-padded to K=32: only quad 0 (k<8) is real.
  half8 w0frag[2];
#pragma unroll
  for (int nt = 0; nt < 2; ++nt) {
    const int n = col0 + nt;
    half8 f;
#pragma unroll
    for (int j = 0; j < 8; ++j) {
      const int k = quad * 8 + j;
      f[j] = (k < 8) ? (_Float16)W0[k * HID + n] : (_Float16)0.f;
    }
    w0frag[nt] = f;
  }
  // biases for this lane's columns
  float b0r[2], rb1r[2], rb2r[2], sb1r[2], sb2r[2];
#pragma unroll
  for (int nt = 0; nt < 2; ++nt) {
    const int n = col0 + nt;
    b0r[nt] = b0[n]; rb1r[nt] = rb1[n]; rb2r[nt] = rb2[n];
    sb1r[nt] = sb1[n]; sb2r[nt] = sb2[n];
  }
  const float bfv = bfp[0];

  // LDS zero-fill (pad cols 8..31 stay zero forever) + Wf + S staging.
  for (int i = tid; i < ROWS * FSTRIDE; i += THREADS) featb[i] = (_Float16)0.f;
  if (tid < HID) WfS[tid] = (_Float16)Wf[tid];
  for (int i = tid; i < ROWS * SLEN; i += THREADS)
    Slds[i] = S[(size_t)r0 * SLEN + i];       // contiguous, coalesced
  __syncthreads();   // zero-fill + S staging complete before feature writes

  // step-0 features (threads 0..31 each own one row; S read from LDS)
  float lm_prev = 0.f, cum_x = 0.f, qv = 0.f;
  const float* Srow = &Slds[(tid & (ROWS - 1)) * SLEN];
  if (tid < ROWS) {
    const float lm = logf(Srow[0] * 0.01f);
    lm_prev = lm; cum_x = lm; qv = 0.f;
    _Float16* fr = &featb[tid * FSTRIDE];
    fr[0] = (_Float16)lm;
    fr[1] = (_Float16)1.0f;
    fr[2] = (_Float16)0.235f;
    fr[3] = (_Float16)0.f;                 // delta_0 = 0
    fr[4] = (_Float16)lm;                  // run_mean at k=0
    fr[5] = (_Float16)0.f;
    fr[6] = (_Float16)(1.9f * sqrtf(1e-12f));
    fr[7] = (_Float16)0.f;
  }
  __syncthreads();

  floatx4 acc[2][2];

#define INIT_BIAS(BR) do { \
  _Pragma("unroll") for (int mt = 0; mt < 2; ++mt) \
  _Pragma("unroll") for (int nt = 0; nt < 2; ++nt) { \
    floatx4 z = {BR[nt], BR[nt], BR[nt], BR[nt]}; acc[mt][nt] = z; } } while (0)

#define INIT_BIAS_RES(BR, RESBUF) do { \
  _Pragma("unroll") for (int mt = 0; mt < 2; ++mt) \
  _Pragma("unroll") for (int r = 0; r < 4; ++r) { \
    const int row = mt * 16 + quad * 4 + r; \
    const fp16x2 h2 = *(const fp16x2*)&RESBUF[row * ASTRIDE + col0]; \
    acc[mt][0][r] = BR[0] + (float)h2[0]; \
    acc[mt][1][r] = BR[1] + (float)h2[1]; \
  } } while (0)

#define GEMM128(SRC, MI) do { \
  _Pragma("unroll") for (int kq = 0; kq < 4; ++kq) { \
    half8 afr[2]; \
    _Pragma("unroll") for (int mt = 0; mt < 2; ++mt) \
      afr[mt] = *(const half8*)&SRC[(mt * 16 + l15) * ASTRIDE + kq * 32 + quad * 8]; \
    _Pragma("unroll") for (int mt = 0; mt < 2; ++mt) \
    _Pragma("unroll") for (int nt = 0; nt < 2; ++nt) \
      acc[mt][nt] = __builtin_amdgcn_mfma_f32_16x16x32_f16( \
          afr[mt], wfrag[MI][kq][nt], acc[mt][nt], 0, 0, 0); \
  } } while (0)

// lrelu in f32, RTN casts, pack pair -> one b32 store
#define EPI_LRELU(DST) do { \
  _Pragma("unroll") for (int mt = 0; mt < 2; ++mt) \
  _Pragma("unroll") for (int r = 0; r < 4; ++r) { \
    const int row = mt * 16 + quad * 4 + r; \
    const float v0 = acc[mt][0][r]; \
    const float v1 = acc[mt][1][r]; \
    fp16x2 h2 = {(__fp16)fmaxf(v0, 0.2f * v0), (__fp16)fmaxf(v1, 0.2f * v1)}; \
    *(fp16x2*)&DST[row * ASTRIDE + col0] = h2; \
  } } while (0)

#define EPI_STORE(DST) do { \
  _Pragma("unroll") for (int mt = 0; mt < 2; ++mt) \
  _Pragma("unroll") for (int r = 0; r < 4; ++r) { \
    const int row = mt * 16 + quad * 4 + r; \
    fp16x2 h2 = {(__fp16)acc[mt][0][r], (__fp16)acc[mt][1][r]}; \
    *(fp16x2*)&DST[row * ASTRIDE + col0] = h2; \
  } } while (0)

#pragma unroll 1
  for (int k = 0; k < NSTEPS; ++k) {
    // G0: h0 = lrelu(featPad @ W0pad + b0)   (featb complete: fr[3] via bar F)
    INIT_BIAS(b0r);
    {
      half8 afr[2];
#pragma unroll
      for (int mt = 0; mt < 2; ++mt)
        afr[mt] = *(const half8*)&featb[(mt * 16 + l15) * FSTRIDE + quad * 8];
#pragma unroll
      for (int mt = 0; mt < 2; ++mt)
#pragma unroll
        for (int nt = 0; nt < 2; ++nt)
          acc[mt][nt] = __builtin_amdgcn_mfma_f32_16x16x32_f16(
              afr[mt], w0frag[nt], acc[mt][nt], 0, 0, 0);
    }
    EPI_LRELU(bufA);
    __syncthreads();                                   // bar A: bufA ready, featb consumed

    // delta-independent features of step k+1 — overlaps the GEMM phase.
    // (Slds[.. k+1] valid at k=63: SLEN=65; write is dead then, harmless.)
    if (tid < ROWS) {
      const int kk = k + 1;
      const float lm = logf(Srow[kk] * 0.01f);
      const float rr = lm - lm_prev; qv += rr * rr;
      lm_prev = lm; cum_x += lm;
      const float tT = (float)kk * (1.f / 64.f);
      _Float16* fr = &featb[tid * FSTRIDE];
      fr[0] = (_Float16)lm;
      fr[1] = (_Float16)(1.f - tT);
      fr[4] = (_Float16)(cum_x / (float)(kk + 1));
      fr[5] = (_Float16)qv;
      fr[6] = (_Float16)(1.9f * sqrtf(qv + 1e-12f));
      fr[7] = (_Float16)tT;
    }

    INIT_BIAS(rb1r);            GEMM128(bufA, 0); EPI_LRELU(bufB);  // u
    __syncthreads();                                   // bar B
    INIT_BIAS_RES(rb2r, bufA);  GEMM128(bufB, 1); EPI_STORE(bufA);  // h1
    __syncthreads();                                   // bar C
    INIT_BIAS(sb1r);            GEMM128(bufA, 2); EPI_LRELU(bufB);  // v
    __syncthreads();                                   // bar D
    INIT_BIAS_RES(sb2r, bufA);  GEMM128(bufB, 3); EPI_STORE(bufA);  // h2
    __syncthreads();                                   // bar E: h2 in bufA

    // delta = sigmoid(h2 @ Wf + bf) via MFMA with broadcast B (all cols = Wf).
    // 32 rows -> waves 0,1 cover rows wave*16 + l15; waves 2,3 idle here.
    if (wave < 2) {
      floatx4 dacc = {0.f, 0.f, 0.f, 0.f};
#pragma unroll
      for (int kq = 0; kq < 4; ++kq) {
        const half8 a  = *(const half8*)&bufA[(wave * 16 + l15) * ASTRIDE + kq * 32 + quad * 8];
        const half8 wv = *(const half8*)&WfS[kq * 32 + quad * 8];   // broadcast read
        dacc = __builtin_amdgcn_mfma_f32_16x16x32_f16(a, wv, dacc, 0, 0, 0);
      }
      if (l15 < 4) {
        // static-index select of dacc[l15] (rule: no runtime vector index)
        const float sv = (l15 & 2) ? ((l15 & 1) ? dacc[3] : dacc[2])
                                   : ((l15 & 1) ? dacc[1] : dacc[0]);
        const int row = wave * 16 + quad * 4 + l15;
        const float d = 1.f / (1.f + expf(-(sv + bfv)));
        featb[row * FSTRIDE + 3] = (_Float16)d;        // fr[3] for step k+1
        deltab[row * DSTR + k] = d;                    // staged output
      }
    }
    __syncthreads();                                   // bar F: featb complete
  }

  // coalesced output flush: 32 rows x 64 steps, dwordx4 stores.
  // (bar F of k=63 made deltab fully visible.)
  {
    const int row = tid >> 3;                // 0..31
    const int c0  = (tid & 7) * 8;           // 0,8,...,56
    const float* dr = &deltab[row * DSTR + c0];
    float* orow = &out[(size_t)(r0 + row) * NSTEPS + c0];
#pragma unroll
    for (int u = 0; u < 2; ++u) {
      const floatx4 v = *(const floatx4*)&dr[u * 4];
      *(floatx4*)&orow[u * 4] = v;
    }
  }
#undef INIT_BIAS
#undef INIT_BIAS_RES
#undef GEMM128
#undef EPI_LRELU
#undef EPI_STORE
}

extern "C" void kernel_launch(void* const* d_in, const int* in_sizes, int n_in,
                              void* d_out, int out_size, void* d_ws, size_t ws_size,
                              hipStream_t stream) {
  const float* S   = (const float*)d_in[0];
  const float* W0  = (const float*)d_in[1];
  const float* b0  = (const float*)d_in[2];
  const float* rW1 = (const float*)d_in[3];
  const float* rb1 = (const float*)d_in[4];
  const float* rW2 = (const float*)d_in[5];
  const float* rb2 = (const float*)d_in[6];
  const float* sW1 = (const float*)d_in[7];
  const float* sb1 = (const float*)d_in[8];
  const float* sW2 = (const float*)d_in[9];
  const float* sb2 = (const float*)d_in[10];
  const float* Wf  = (const float*)d_in[11];
  const float* bf  = (const float*)d_in[12];
  float* out = (float*)d_out;

  const int B = out_size / NSTEPS;        // 32768
  const int nblocks = B / ROWS;           // 1024 WGs -> 4 per CU
  hedger<<<nblocks, THREADS, 0, stream>>>(
      S, W0, b0, rW1, rb1, rW2, rb2, sW1, sb1, sW2, sb2, Wf, bf, out);
}

// Round 4
// 550.651 us; speedup vs baseline: 1.9567x; 1.9567x over previous
//
#include <hip/hip_runtime.h>
#include <math.h>

#define HID 128
#define NSTEPS 64
#define SLEN 65
#define THREADS 512   // R16: 8 waves/WG, 16 cols/wave
#define ROWS 64
#define ASTRIDE 136   // 128 + 8 f16 pad, 16B aligned rows
#define FSTRIDE 40    // 32 + 8 f16 pad
#define DSTR 68       // 64 + 4 f32 pad, 16B-aligned rows for b128 flush reads

typedef _Float16 half8 __attribute__((ext_vector_type(8)));
typedef __fp16 fp16x2 __attribute__((ext_vector_type(2)));
typedef float floatx4 __attribute__((ext_vector_type(4)));

// R16: occupancy experiment done RIGHT. R15 failed because launch_bounds(,4)
// capped VGPR at 128 while the 32-col/wave design needs ~190 -> wfrag spilled
// to scratch (VGPR_Count 64, FETCH 3.2GB, 2.7x regression). Fix the register
// budget, not the bound: 8 waves x 16 cols/wave halves wfrag to 64 VGPR;
// w0frag and biases move to LDS; est. peak live ~118 <= 128. Grid stays 512
// (ROWS=64) -> 2 WGs/CU x 8 waves = 4 waves/SIMD, double the latency-hiding
// across the same 6-barrier structure, with ZERO LDS weight traffic kept.
// Known cost: A-frag LDS reads double (more waves read the same rows).
// Numerics identical to R13 (same rounding points).
// CLOSED: 32-col/wave + any min-waves>2 bound (spill, R15); XOR swizzle
// (R14: SQ_LDS_BANK_CONFLICT is structural b128 serialization, bit-identical
// 3.808e7 across layouts); residual-in-regs (R10/R11 spill); 32x32 MFMA;
// 6 barriers = dependency minimum. VGPR_Count CSV lies about spill — watch
// FETCH/WRITE_SIZE.
__global__ __launch_bounds__(THREADS, 4)
void hedger(const float* __restrict__ S,
            const float* __restrict__ W0,  const float* __restrict__ b0,
            const float* __restrict__ rW1, const float* __restrict__ rb1,
            const float* __restrict__ rW2, const float* __restrict__ rb2,
            const float* __restrict__ sW1, const float* __restrict__ sb1,
            const float* __restrict__ sW2, const float* __restrict__ sb2,
            const float* __restrict__ Wf,  const float* __restrict__ bfp,
            float* __restrict__ out)
{
  __shared__ __align__(16) _Float16 bufA[ROWS * ASTRIDE];   // 17408 B
  __shared__ __align__(16) _Float16 bufB[ROWS * ASTRIDE];   // 17408 B
  __shared__ __align__(16) _Float16 featb[ROWS * FSTRIDE];  //  5120 B
  __shared__ __align__(16) _Float16 WfS[HID];               //   256 B
  __shared__ __align__(16) _Float16 W0B[HID * 8];           //  2048 B  [col][j] = W0[j][col]
  __shared__ __align__(16) float    biasL[5 * HID];         //  2560 B  b0,rb1,rb2,sb1,sb2
  __shared__ __align__(16) float    Slds[ROWS * SLEN];      // 16640 B
  __shared__ __align__(16) float    deltab[ROWS * DSTR];    // 17408 B
  // total 78848 B/WG -> 2 WGs/CU fits in 160 KiB

  const int tid  = threadIdx.x;
  const int wave = tid >> 6;            // 0..7
  const int lane = tid & 63;
  const int l15  = lane & 15;
  const int quad = lane >> 4;
  const int col  = wave * 16 + l15;     // lane's single output column
  const int r0   = blockIdx.x * ROWS;

  // ---- persistent B fragments (64 VGPR): k = quad*8 + j, n = col.
  half8 wfrag[4][4];  // [matrix][kIter]
  {
    const float* Wm[4] = {rW1, rW2, sW1, sW2};
#pragma unroll
    for (int m = 0; m < 4; ++m)
#pragma unroll
      for (int kq = 0; kq < 4; ++kq) {
        const int kb = kq * 32 + quad * 8;
        half8 f;
#pragma unroll
        for (int j = 0; j < 8; ++j)
          f[j] = (_Float16)Wm[m][(kb + j) * HID + col];
        wfrag[m][kq] = f;
      }
  }
  const float bfv = bfp[0];

  // LDS init: featb zero-fill (pad cols 8..31 stay zero), Wf, W0B (B-frag
  // friendly transpose: W0B[c*8+j] = W0[j][c]), biases, S staging.
  for (int i = tid; i < ROWS * FSTRIDE; i += THREADS) featb[i] = (_Float16)0.f;
  if (tid < HID) {
    WfS[tid] = (_Float16)Wf[tid];
#pragma unroll
    for (int j = 0; j < 8; ++j) W0B[tid * 8 + j] = (_Float16)W0[j * HID + tid];
    biasL[0 * HID + tid] = b0[tid];
    biasL[1 * HID + tid] = rb1[tid];
    biasL[2 * HID + tid] = rb2[tid];
    biasL[3 * HID + tid] = sb1[tid];
    biasL[4 * HID + tid] = sb2[tid];
  }
  for (int i = tid; i < ROWS * SLEN; i += THREADS)
    Slds[i] = S[(size_t)r0 * SLEN + i];       // contiguous, coalesced
  __syncthreads();   // init complete before feature writes

  // step-0 features (threads 0..63 = wave 0, one row each; S read from LDS)
  float lm_prev = 0.f, cum_x = 0.f, qv = 0.f;
  const float* Srow = &Slds[(tid & (ROWS - 1)) * SLEN];
  if (tid < ROWS) {
    const float lm = logf(Srow[0] * 0.01f);
    lm_prev = lm; cum_x = lm; qv = 0.f;
    _Float16* fr = &featb[tid * FSTRIDE];
    fr[0] = (_Float16)lm;
    fr[1] = (_Float16)1.0f;
    fr[2] = (_Float16)0.235f;
    fr[3] = (_Float16)0.f;                 // delta_0 = 0
    fr[4] = (_Float16)lm;                  // run_mean at k=0
    fr[5] = (_Float16)0.f;
    fr[6] = (_Float16)(1.9f * sqrtf(1e-12f));
    fr[7] = (_Float16)0.f;
  }
  __syncthreads();

  floatx4 acc[4];    // [mt]: rows mt*16 + quad*4 + r, col = col

#define INIT_BIAS(BI) do { \
  const float bv = biasL[(BI) * HID + col]; \
  _Pragma("unroll") for (int mt = 0; mt < 4; ++mt) { \
    floatx4 z = {bv, bv, bv, bv}; acc[mt] = z; } } while (0)

#define INIT_BIAS_RES(BI, RESBUF) do { \
  const float bv = biasL[(BI) * HID + col]; \
  _Pragma("unroll") for (int mt = 0; mt < 4; ++mt) \
  _Pragma("unroll") for (int r = 0; r < 4; ++r) { \
    const int row = mt * 16 + quad * 4 + r; \
    acc[mt][r] = bv + (float)RESBUF[row * ASTRIDE + col]; \
  } } while (0)

#define GEMM128(SRC, MI) do { \
  _Pragma("unroll") for (int kq = 0; kq < 4; ++kq) { \
    half8 afr[4]; \
    _Pragma("unroll") for (int mt = 0; mt < 4; ++mt) \
      afr[mt] = *(const half8*)&SRC[(mt * 16 + l15) * ASTRIDE + kq * 32 + quad * 8]; \
    _Pragma("unroll") for (int mt = 0; mt < 4; ++mt) \
      acc[mt] = __builtin_amdgcn_mfma_f32_16x16x32_f16( \
          afr[mt], wfrag[MI][kq], acc[mt], 0, 0, 0); \
  } } while (0)

// lrelu in f32, RTN casts, single b16 store per value (conflict-free:
// quad q writes banks 8q..8q+7 within its wave's 16-col slice)
#define EPI_LRELU(DST) do { \
  _Pragma("unroll") for (int mt = 0; mt < 4; ++mt) \
  _Pragma("unroll") for (int r = 0; r < 4; ++r) { \
    const int row = mt * 16 + quad * 4 + r; \
    const float v0 = acc[mt][r]; \
    DST[row * ASTRIDE + col] = (_Float16)fmaxf(v0, 0.2f * v0); \
  } } while (0)

#define EPI_STORE(DST) do { \
  _Pragma("unroll") for (int mt = 0; mt < 4; ++mt) \
  _Pragma("unroll") for (int r = 0; r < 4; ++r) { \
    const int row = mt * 16 + quad * 4 + r; \
    DST[row * ASTRIDE + col] = (_Float16)acc[mt][r]; \
  } } while (0)

#pragma unroll 1
  for (int k = 0; k < NSTEPS; ++k) {
    // G0: h0 = lrelu(featPad @ W0pad + b0). W0 B-frag from LDS (one b128,
    // quads 1..3 supply the K-pad zeros).
    INIT_BIAS(0);
    {
      half8 w0f;
      if (quad == 0) w0f = *(const half8*)&W0B[col * 8];
      else { half8 z = {0,0,0,0,0,0,0,0}; w0f = z; }
      half8 afr[4];
#pragma unroll
      for (int mt = 0; mt < 4; ++mt)
        afr[mt] = *(const half8*)&featb[(mt * 16 + l15) * FSTRIDE + quad * 8];
#pragma unroll
      for (int mt = 0; mt < 4; ++mt)
        acc[mt] = __builtin_amdgcn_mfma_f32_16x16x32_f16(
            afr[mt], w0f, acc[mt], 0, 0, 0);
    }
    EPI_LRELU(bufA);
    __syncthreads();                                   // bar A: bufA ready, featb consumed

    // delta-independent features of step k+1 — overlaps the GEMM phase.
    // (Slds[.. k+1] valid at k=63: SLEN=65; write is dead then, harmless.)
    if (tid < ROWS) {
      const int kk = k + 1;
      const float lm = logf(Srow[kk] * 0.01f);
      const float rr = lm - lm_prev; qv += rr * rr;
      lm_prev = lm; cum_x += lm;
      const float tT = (float)kk * (1.f / 64.f);
      _Float16* fr = &featb[tid * FSTRIDE];
      fr[0] = (_Float16)lm;
      fr[1] = (_Float16)(1.f - tT);
      fr[4] = (_Float16)(cum_x / (float)(kk + 1));
      fr[5] = (_Float16)qv;
      fr[6] = (_Float16)(1.9f * sqrtf(qv + 1e-12f));
      fr[7] = (_Float16)tT;
    }

    INIT_BIAS(1);               GEMM128(bufA, 0); EPI_LRELU(bufB);  // u
    __syncthreads();                                   // bar B
    INIT_BIAS_RES(2, bufA);     GEMM128(bufB, 1); EPI_STORE(bufA);  // h1
    __syncthreads();                                   // bar C
    INIT_BIAS(3);               GEMM128(bufA, 2); EPI_LRELU(bufB);  // v
    __syncthreads();                                   // bar D
    INIT_BIAS_RES(4, bufA);     GEMM128(bufB, 3); EPI_STORE(bufA);  // h2
    __syncthreads();                                   // bar E: h2 in bufA

    // delta = sigmoid(h2 @ Wf + bf) via MFMA with broadcast B (all cols =
    // Wf). Waves 0..3 cover the 64 rows (rows wave*16 + quad*4 + r).
    if (wave < 4) {
      floatx4 dacc = {0.f, 0.f, 0.f, 0.f};
#pragma unroll
      for (int kq = 0; kq < 4; ++kq) {
        const half8 a  = *(const half8*)&bufA[(wave * 16 + l15) * ASTRIDE + kq * 32 + quad * 8];
        const half8 wv = *(const half8*)&WfS[kq * 32 + quad * 8];   // broadcast read
        dacc = __builtin_amdgcn_mfma_f32_16x16x32_f16(a, wv, dacc, 0, 0, 0);
      }
      if (l15 < 4) {
        // static-index select of dacc[l15] (rule: no runtime vector index)
        const float sv = (l15 & 2) ? ((l15 & 1) ? dacc[3] : dacc[2])
                                   : ((l15 & 1) ? dacc[1] : dacc[0]);
        const int row = wave * 16 + quad * 4 + l15;
        const float d = 1.f / (1.f + expf(-(sv + bfv)));
        featb[row * FSTRIDE + 3] = (_Float16)d;        // fr[3] for step k+1
        deltab[row * DSTR + k] = d;                    // staged output
      }
    }
    __syncthreads();                                   // bar F: featb complete
  }

  // coalesced output flush: 64 rows x 64 steps, dwordx4 stores.
  // (bar F of k=63 made deltab fully visible.)
  {
    const int row = tid >> 3;                // 0..63
    const int c0  = (tid & 7) * 8;           // 0,8,...,56
    const float* dr = &deltab[row * DSTR + c0];
    float* orow = &out[(size_t)(r0 + row) * NSTEPS + c0];
#pragma unroll
    for (int u = 0; u < 2; ++u) {
      const floatx4 v = *(const floatx4*)&dr[u * 4];
      *(floatx4*)&orow[u * 4] = v;
    }
  }
#undef INIT_BIAS
#undef INIT_BIAS_RES
#undef GEMM128
#undef EPI_LRELU
#undef EPI_STORE
}

extern "C" void kernel_launch(void* const* d_in, const int* in_sizes, int n_in,
                              void* d_out, int out_size, void* d_ws, size_t ws_size,
                              hipStream_t stream) {
  const float* S   = (const float*)d_in[0];
  const float* W0  = (const float*)d_in[1];
  const float* b0  = (const float*)d_in[2];
  const float* rW1 = (const float*)d_in[3];
  const float* rb1 = (const float*)d_in[4];
  const float* rW2 = (const float*)d_in[5];
  const float* rb2 = (const float*)d_in[6];
  const float* sW1 = (const float*)d_in[7];
  const float* sb1 = (const float*)d_in[8];
  const float* sW2 = (const float*)d_in[9];
  const float* sb2 = (const float*)d_in[10];
  const float* Wf  = (const float*)d_in[11];
  const float* bf  = (const float*)d_in[12];
  float* out = (float*)d_out;

  const int B = out_size / NSTEPS;        // 32768
  const int nblocks = B / ROWS;           // 512 WGs -> 2 per CU
  hedger<<<nblocks, THREADS, 0, stream>>>(
      S, W0, b0, rW1, rb1, rW2, rb2, sW1, sb1, sW2, sb2, Wf, bf, out);
}